// Round 5
// baseline (358.608 us; speedup 1.0000x reference)
//
#include <hip/hip_runtime.h>

#define EE 512
#define HH 256
#define QQ 1024
#define SS 512
#define NSTEPS 3
#define NBLK 512

// ---------------------------------------------------------------------------
// Workspace grid barrier, cache-maintenance-minimal.
// Layout (128B-separated lines): bar[0]=generation, bar[32]/bar[64]=ping-pong
// arrival counters. All zeroed by hipMemsetAsync before launch (graph-safe).
// Per block per barrier: 1 release fence (wbL2) -> relaxed fetch_add arrival
// -> relaxed agent-scope polls (execute at coherence point, no per-poll cache
// maintenance) -> 1 acquire fence (invL2) after flip. Ping-pong counters make
// the counter reset race-free across generations.
// 512 blocks = 2/CU: LDS 24.4KB -> capacity 6/CU, VGPR 92 -> no limit, so all
// blocks are co-resident and the barrier cannot deadlock.
// ---------------------------------------------------------------------------
__device__ __forceinline__ void gbar(unsigned int* bar, unsigned int* gen) {
    __syncthreads();
    if (threadIdx.x == 0) {
        const unsigned int g = *gen;
        unsigned int* cnt = &bar[32 + ((g & 1u) << 5)];
        __builtin_amdgcn_fence(__ATOMIC_RELEASE, "agent");   // wb my writes
        unsigned int arrived = __hip_atomic_fetch_add(
            cnt, 1u, __ATOMIC_RELAXED, __HIP_MEMORY_SCOPE_AGENT);
        if (arrived == NBLK - 1u) {
            __hip_atomic_store(cnt, 0u, __ATOMIC_RELAXED,
                               __HIP_MEMORY_SCOPE_AGENT);
            __hip_atomic_store(&bar[0], g + 1u, __ATOMIC_RELEASE,
                               __HIP_MEMORY_SCOPE_AGENT);   // orders reset first
        } else {
            while (__hip_atomic_load(&bar[0], __ATOMIC_RELAXED,
                                     __HIP_MEMORY_SCOPE_AGENT) < g + 1u) {
                __builtin_amdgcn_s_sleep(1);
            }
        }
        __builtin_amdgcn_fence(__ATOMIC_ACQUIRE, "agent");   // drop stale lines
        *gen = g + 1u;
    }
    __syncthreads();
}

// ---------------------------------------------------------------------------
// 32x64 GEMM tile engine: 256 threads, BK=32, register-prefetch double
// buffering. X-tile stored K-MAJOR (Xs[k][m], stride 66) so the inner loop is
// ds_read_b64 (2 consecutive rows) + ds_read_b128 (4 cols) per kk.
// acc[2][4]: rows m0+2*ty{+0,1}, cols n0+4*tx..+3.
// ---------------------------------------------------------------------------
__device__ __forceinline__ void mm_tile(const float* __restrict__ Xrow, int K,
                                        const float* __restrict__ Wcol, int N,
                                        float (*Xs)[66], float (*Ws)[68],
                                        float acc[2][4]) {
    const int tid = threadIdx.x;
    const int r   = tid >> 3;          // 0..31
    const int c4  = (tid & 7) << 2;    // X k-chunk
    const int c8  = (tid & 7) << 3;    // W n-chunk
    const int tx  = tid & 15;
    const int ty2 = (tid >> 4) << 1;   // row pair base

    float4 vx  = *(const float4*)&Xrow[r * K + c4];
    float4 vw0 = *(const float4*)&Wcol[r * N + c8];
    float4 vw1 = *(const float4*)&Wcol[r * N + c8 + 4];

    for (int k0 = 0; k0 < K; k0 += 32) {
        Xs[c4 + 0][r] = vx.x;          // k-major scatter (2-way conflicts max)
        Xs[c4 + 1][r] = vx.y;
        Xs[c4 + 2][r] = vx.z;
        Xs[c4 + 3][r] = vx.w;
        *(float4*)&Ws[r][c8]     = vw0;
        *(float4*)&Ws[r][c8 + 4] = vw1;
        __syncthreads();
        if (k0 + 32 < K) {   // prefetch next K-tile while FMAs run
            vx  = *(const float4*)&Xrow[r * K + k0 + 32 + c4];
            vw0 = *(const float4*)&Wcol[(k0 + 32 + r) * N + c8];
            vw1 = *(const float4*)&Wcol[(k0 + 32 + r) * N + c8 + 4];
        }
        #pragma unroll
        for (int kk = 0; kk < 32; kk++) {
            float4 b = *(const float4*)&Ws[kk][tx << 2];
            float2 a = *(const float2*)&Xs[kk][ty2];
            acc[0][0] += a.x * b.x; acc[0][1] += a.x * b.y;
            acc[0][2] += a.x * b.z; acc[0][3] += a.x * b.w;
            acc[1][0] += a.y * b.x; acc[1][1] += a.y * b.y;
            acc[1][2] += a.y * b.z; acc[1][3] += a.y * b.w;
        }
        __syncthreads();
    }
}

struct KArgs {
    const float* qf;  const float* sf;  const int* y;
    const float* Wn1; const float* bn1; const float* Wn2; const float* bn2;
    const float* Wm1; const float* bm1; const float* Wm2; const float* bm2;
    const float* Wr1; const float* br1; const float* wr2; const float* br2;
    float* out; float* ws;
};

// ---------------------------------------------------------------------------
// Single persistent kernel, plain launch. 512 blocks x 256 threads (2/CU for
// latency hiding -- R4 at 1 block/CU was latency-bound, VALUBusy 9.7%).
// Phases separated by the workspace grid barrier:
//  P0 enc1(192 tiles)+stats | P1 enc2(192) |
//  [ab(128)+hq(128,t==0) | hsum(512) | gagg(64)] x3 | hsT(64) | scores(512)
// ---------------------------------------------------------------------------
__global__ __launch_bounds__(256) void fused_k(KArgs a) {
    __shared__ float Xs[32][66];
    __shared__ float Ws[32][68];
    __shared__ int   lst[SS];
    __shared__ int   info[2];
    __shared__ int   lc[16];
    __shared__ float hqs[4][HH];
    __shared__ float w2s[HH];

    float* F    = a.ws;
    float* X1   = F + 0;             // 1536*256 (dead after enc2)
    float* QS   = F + 393216;        // 1536*256
    float* q    = QS;                // 1024*256
    float* s    = QS + QQ * HH;      // 512*256
    float* A    = F + 786432;        // 512*256
    float* Bm   = F + 917504;        // 512*256
    float* hsum = F + 1048576;       // 512*256
    float* hq   = F + 0;             // 1024*256 (reuses dead X1)
    float* hsT  = F + 262144;        // 256*512  (inside dead X1)
    float* cntf = F + 1179648;       // 512
    float* invd = F + 1180160;       // 512
    int*  icls  = (int*)(F + 1180672);
    int*  cls_cnt  = icls;           // 16
    int*  cls_list = icls + 16;      // 16*512
    unsigned int* bar = (unsigned int*)(F + 1200128);  // zeroed by host memset

    const int tid = threadIdx.x;
    const int bid = blockIdx.x;
    const int tx  = tid & 15, ty2 = (tid >> 4) << 1;
    unsigned int gen = 0;            // barrier generation (thread 0's copy used)

    // ---------------- P0: enc1 (relu(x@Wn1+bn1)) + mask statistics ---------
    if (bid < 192) {
        const int m0 = (bid >> 2) << 5;
        const int n0 = (bid & 3) << 6;
        const float* Xrow = (m0 < QQ) ? (a.qf + m0 * EE) : (a.sf + (m0 - QQ) * EE);
        float acc[2][4] = {{0,0,0,0},{0,0,0,0}};
        mm_tile(Xrow, EE, a.Wn1 + n0, HH, Xs, Ws, acc);
        #pragma unroll
        for (int rr = 0; rr < 2; rr++) {
            int m = m0 + ty2 + rr;
            int n = n0 + (tx << 2);
            float4 o;
            o.x = fmaxf(acc[rr][0] + a.bn1[n + 0], 0.f);
            o.y = fmaxf(acc[rr][1] + a.bn1[n + 1], 0.f);
            o.z = fmaxf(acc[rr][2] + a.bn1[n + 2], 0.f);
            o.w = fmaxf(acc[rr][3] + a.bn1[n + 3], 0.f);
            *(float4*)&X1[m * HH + n] = o;
        }
    } else if (bid == 192) {
        if (tid < 16) lc[tid] = 0;
        __syncthreads();
        for (int i = tid; i < SS; i += 256) {
            int c = a.y[i];
            int slot = atomicAdd(&lc[c], 1);
            cls_list[c * SS + slot] = i;
        }
        __syncthreads();
        if (tid < 16) cls_cnt[tid] = lc[tid];
        for (int i = tid; i < SS; i += 256) {
            float n = (float)(lc[a.y[i]] - 1);
            cntf[i] = n;
            invd[i] = 1.f / fmaxf(n, 1.f);
        }
    }
    gbar(bar, &gen);

    // ---------------- P1: enc2 (X1@Wn2+bn2) -> QS --------------------------
    if (bid < 192) {
        const int m0 = (bid >> 2) << 5;
        const int n0 = (bid & 3) << 6;
        float acc[2][4] = {{0,0,0,0},{0,0,0,0}};
        mm_tile(X1 + m0 * HH, HH, a.Wn2 + n0, HH, Xs, Ws, acc);
        #pragma unroll
        for (int rr = 0; rr < 2; rr++) {
            int m = m0 + ty2 + rr;
            int n = n0 + (tx << 2);
            float4 o;
            o.x = acc[rr][0] + a.bn2[n + 0];
            o.y = acc[rr][1] + a.bn2[n + 1];
            o.z = acc[rr][2] + a.bn2[n + 2];
            o.w = acc[rr][3] + a.bn2[n + 3];
            *(float4*)&QS[m * HH + n] = o;
        }
    }
    gbar(bar, &gen);

    // ---------------- message passing --------------------------------------
    for (int t = 0; t < NSTEPS; t++) {
        const float* W1t = a.Wm1 + t * 2 * HH * HH;
        const float* b1t = a.bm1 + t * HH;
        const float* W2t = a.Wm2 + t * HH * HH;
        const float* b2t = a.bm2 + t * HH;

        // ab: A = s@W1a, B = s@W1b  (+ hq = q@Wr1a co-scheduled at t==0)
        if (bid < 128) {
            int nt = bid & 7;
            const int m0 = (bid >> 3) << 5;
            const float* W = W1t;
            float* C = A;
            if (nt >= 4) { nt -= 4; W = W1t + HH * HH; C = Bm; }
            const int n0 = nt << 6;
            float acc[2][4] = {{0,0,0,0},{0,0,0,0}};
            mm_tile(s + m0 * HH, HH, W + n0, HH, Xs, Ws, acc);
            #pragma unroll
            for (int rr = 0; rr < 2; rr++) {
                int m = m0 + ty2 + rr;
                int n = n0 + (tx << 2);
                float4 o = { acc[rr][0], acc[rr][1], acc[rr][2], acc[rr][3] };
                *(float4*)&C[m * HH + n] = o;
            }
        } else if (t == 0 && bid < 256) {
            const int idx = bid - 128;        // 0..127
            const int m0 = (idx >> 2) << 5;   // 32 row tiles over Q=1024
            const int n0 = (idx & 3) << 6;
            float acc[2][4] = {{0,0,0,0},{0,0,0,0}};
            mm_tile(q + m0 * HH, HH, a.Wr1 + n0, HH, Xs, Ws, acc);
            #pragma unroll
            for (int rr = 0; rr < 2; rr++) {
                int m = m0 + ty2 + rr;
                int n = n0 + (tx << 2);
                float4 o = { acc[rr][0], acc[rr][1], acc[rr][2], acc[rr][3] };
                *(float4*)&hq[m * HH + n] = o;
            }
        }
        gbar(bar, &gen);

        // hsum: one support row per block
        {
            const int i = bid;
            const int h = tid;
            if (h == 0) { int yi = a.y[i]; info[0] = yi; info[1] = cls_cnt[yi]; }
            __syncthreads();
            const int cnt = info[1];
            const int* Lp = cls_list + info[0] * SS;
            for (int m = h; m < cnt; m += 256) lst[m] = Lp[m];
            __syncthreads();
            const float av = A[i * HH + h] + b1t[h];
            float acc = 0.f;
            int m = 0;
            for (; m + 4 <= cnt; m += 4) {          // 4 loads in flight
                float v0 = Bm[lst[m + 0] * HH + h];
                float v1 = Bm[lst[m + 1] * HH + h];
                float v2 = Bm[lst[m + 2] * HH + h];
                float v3 = Bm[lst[m + 3] * HH + h];
                acc += fmaxf(av + v0, 0.f) + fmaxf(av + v1, 0.f)
                     + fmaxf(av + v2, 0.f) + fmaxf(av + v3, 0.f);
            }
            for (; m < cnt; m++) acc += fmaxf(av + Bm[lst[m] * HH + h], 0.f);
            acc -= fmaxf(av + Bm[i * HH + h], 0.f);  // remove self term
            hsum[i * HH + h] = acc;
        }
        gbar(bar, &gen);

        // gagg: s += (hsum@W2 + cnt*bm2) * invd
        if (bid < 64) {
            const int m0 = (bid >> 2) << 5;
            const int n0 = (bid & 3) << 6;
            float acc[2][4] = {{0,0,0,0},{0,0,0,0}};
            mm_tile(hsum + m0 * HH, HH, W2t + n0, HH, Xs, Ws, acc);
            #pragma unroll
            for (int rr = 0; rr < 2; rr++) {
                int m = m0 + ty2 + rr;
                int n = n0 + (tx << 2);
                float ci = cntf[m], di = invd[m];
                float* sp = &s[m * HH + n];
                float4 sv = *(float4*)sp;
                float4 o;
                o.x = sv.x + (acc[rr][0] + ci * b2t[n + 0]) * di;
                o.y = sv.y + (acc[rr][1] + ci * b2t[n + 1]) * di;
                o.z = sv.z + (acc[rr][2] + ci * b2t[n + 2]) * di;
                o.w = sv.w + (acc[rr][3] + ci * b2t[n + 3]) * di;
                *(float4*)sp = o;
            }
        }
        gbar(bar, &gen);
    }

    // ---------------- hsT[h][j] = (s@Wr1b)[j][h] + br1[h] -------------------
    if (bid < 64) {
        const int m0 = (bid >> 2) << 5;
        const int n0 = (bid & 3) << 6;
        float acc[2][4] = {{0,0,0,0},{0,0,0,0}};
        mm_tile(s + m0 * HH, HH, a.Wr1 + HH * HH + n0, HH, Xs, Ws, acc);
        #pragma unroll
        for (int rr = 0; rr < 2; rr++) {
            int m = m0 + ty2 + rr;
            #pragma unroll
            for (int c = 0; c < 4; c++) {
                int n = n0 + (tx << 2) + c;
                hsT[n * SS + m] = acc[rr][c] + a.br1[n];
            }
        }
    }
    gbar(bar, &gen);

    // ---------------- scores: 4 hq rows, one j-half per block --------------
    {
        const int i0 = (bid >> 1) << 2;
        const int j  = ((bid & 1) << 8) + tid;
        w2s[tid] = a.wr2[tid];
        #pragma unroll
        for (int ii = 0; ii < 4; ii++) hqs[ii][tid] = hq[(i0 + ii) * HH + tid];
        __syncthreads();
        float acc[4] = {0, 0, 0, 0};
        for (int h0 = 0; h0 < HH; h0 += 8) {
            float v[8];
            #pragma unroll
            for (int u = 0; u < 8; u++) v[u] = hsT[(h0 + u) * SS + j];
            float4 w0 = *(const float4*)&w2s[h0];
            float4 w1 = *(const float4*)&w2s[h0 + 4];
            #pragma unroll
            for (int ii = 0; ii < 4; ii++) {
                float4 a0 = *(const float4*)&hqs[ii][h0];
                float4 a1 = *(const float4*)&hqs[ii][h0 + 4];
                acc[ii] += fmaxf(v[0] + a0.x, 0.f) * w0.x
                         + fmaxf(v[1] + a0.y, 0.f) * w0.y
                         + fmaxf(v[2] + a0.z, 0.f) * w0.z
                         + fmaxf(v[3] + a0.w, 0.f) * w0.w
                         + fmaxf(v[4] + a1.x, 0.f) * w1.x
                         + fmaxf(v[5] + a1.y, 0.f) * w1.y
                         + fmaxf(v[6] + a1.z, 0.f) * w1.z
                         + fmaxf(v[7] + a1.w, 0.f) * w1.w;
            }
        }
        float b2 = a.br2[0];
        #pragma unroll
        for (int ii = 0; ii < 4; ii++)
            a.out[(i0 + ii) * SS + j] = acc[ii] + b2;
    }
}

extern "C" void kernel_launch(void* const* d_in, const int* in_sizes, int n_in,
                              void* d_out, int out_size, void* d_ws, size_t ws_size,
                              hipStream_t stream) {
    KArgs ka;
    ka.qf  = (const float*)d_in[0];
    ka.sf  = (const float*)d_in[1];
    ka.y   = (const int*)d_in[2];
    ka.Wn1 = (const float*)d_in[3];
    ka.bn1 = (const float*)d_in[4];
    ka.Wn2 = (const float*)d_in[5];
    ka.bn2 = (const float*)d_in[6];
    ka.Wm1 = (const float*)d_in[7];
    ka.bm1 = (const float*)d_in[8];
    ka.Wm2 = (const float*)d_in[9];
    ka.bm2 = (const float*)d_in[10];
    ka.Wr1 = (const float*)d_in[11];
    ka.br1 = (const float*)d_in[12];
    ka.wr2 = (const float*)d_in[13];
    ka.br2 = (const float*)d_in[14];
    ka.out = (float*)d_out;
    ka.ws  = (float*)d_ws;

    // zero the grid-barrier state (gen + ping-pong counters, 3 cache lines)
    hipMemsetAsync((char*)d_ws + 1200128u * sizeof(float), 0, 384, stream);

    fused_k<<<dim3(NBLK), dim3(256), 0, stream>>>(ka);
}

// Round 6
// 279.797 us; speedup vs baseline: 1.2817x; 1.2817x over previous
//
#include <hip/hip_runtime.h>

#define EE 512
#define HH 256
#define QQ 1024
#define SS 512
#define NSTEPS 3
#define NBLK 256

// ---------------------------------------------------------------------------
// Coherent (agent-scope, sc1) scalar access helpers for kernel-written
// intermediates. Relaxed agent atomics compile to global_load/store sc1:
// they read/write the device coherence point (LLC) directly -- cross-XCD
// visible with NO cache-maintenance fences (same mechanism that makes
// device-scope atomicAdd correct). Weights/inputs use plain cached loads
// and stay L2-hot across phases because nothing invalidates L2 anymore.
// ---------------------------------------------------------------------------
__device__ __forceinline__ float ldc(const float* p) {
    return __hip_atomic_load(p, __ATOMIC_RELAXED, __HIP_MEMORY_SCOPE_AGENT);
}
__device__ __forceinline__ void stc(float* p, float v) {
    __hip_atomic_store(p, v, __ATOMIC_RELAXED, __HIP_MEMORY_SCOPE_AGENT);
}
__device__ __forceinline__ int ldci(const int* p) {
    return __hip_atomic_load(p, __ATOMIC_RELAXED, __HIP_MEMORY_SCOPE_AGENT);
}
__device__ __forceinline__ void stci(int* p, int v) {
    __hip_atomic_store(p, v, __ATOMIC_RELAXED, __HIP_MEMORY_SCOPE_AGENT);
}

// ---------------------------------------------------------------------------
// Fence-free grid barrier. R3/R4/R5 post-mortem: agent release/acquire
// fences emit buffer_wbl2/buffer_inv L2 tag walks (~10us each) -- that WAS
// the barrier cost (and the launch-boundary cost of the 13-kernel version).
// With all cross-phase data going through sc1 (coherence point), the barrier
// needs only: __syncthreads (compiler drains vmcnt -> sc1 stores complete)
// -> relaxed arrival -> relaxed poll -> __syncthreads. The last arriver
// drains its counter-reset store before flipping the generation (ordering
// without a cache walk). Ping-pong counters across generations.
// ---------------------------------------------------------------------------
__device__ __forceinline__ void gbar(unsigned int* bar, unsigned int* gen) {
    __syncthreads();                       // drains vmcnt: stores at LLC
    if (threadIdx.x == 0) {
        const unsigned int g = *gen;
        unsigned int* cnt = &bar[32 + ((g & 1u) << 5)];
        unsigned int arrived = __hip_atomic_fetch_add(
            cnt, 1u, __ATOMIC_RELAXED, __HIP_MEMORY_SCOPE_AGENT);
        if (arrived == NBLK - 1u) {
            __hip_atomic_store(cnt, 0u, __ATOMIC_RELAXED,
                               __HIP_MEMORY_SCOPE_AGENT);
            asm volatile("s_waitcnt vmcnt(0)" ::: "memory"); // reset lands 1st
            __hip_atomic_store(&bar[0], g + 1u, __ATOMIC_RELAXED,
                               __HIP_MEMORY_SCOPE_AGENT);
        } else {
            while (__hip_atomic_load(&bar[0], __ATOMIC_RELAXED,
                                     __HIP_MEMORY_SCOPE_AGENT) < g + 1u) {
                __builtin_amdgcn_s_sleep(2);
            }
        }
        *gen = g + 1u;
    }
    __syncthreads();
}

// ---------------------------------------------------------------------------
// 32x64 GEMM tile engine: 256 threads, BK=32, register-prefetch double
// buffering. X-tile stored K-MAJOR (Xs[k][m], stride 66). XC: X is a
// kernel-written intermediate -> stage via 4 scalar sc1 loads (same prefetch
// slot, latency hidden under the FMA loop). W is always a weight (plain).
// ---------------------------------------------------------------------------
template <bool XC>
__device__ __forceinline__ void mm_tile(const float* __restrict__ Xrow, int K,
                                        const float* __restrict__ Wcol, int N,
                                        float (*Xs)[66], float (*Ws)[68],
                                        float acc[2][4]) {
    const int tid = threadIdx.x;
    const int r   = tid >> 3;          // 0..31
    const int c4  = (tid & 7) << 2;    // X k-chunk
    const int c8  = (tid & 7) << 3;    // W n-chunk
    const int tx  = tid & 15;
    const int ty2 = (tid >> 4) << 1;   // row pair base

    float4 vx;
    if (XC) {
        vx.x = ldc(&Xrow[r * K + c4 + 0]);
        vx.y = ldc(&Xrow[r * K + c4 + 1]);
        vx.z = ldc(&Xrow[r * K + c4 + 2]);
        vx.w = ldc(&Xrow[r * K + c4 + 3]);
    } else {
        vx = *(const float4*)&Xrow[r * K + c4];
    }
    float4 vw0 = *(const float4*)&Wcol[r * N + c8];
    float4 vw1 = *(const float4*)&Wcol[r * N + c8 + 4];

    for (int k0 = 0; k0 < K; k0 += 32) {
        Xs[c4 + 0][r] = vx.x;          // k-major scatter (2-way conflicts max)
        Xs[c4 + 1][r] = vx.y;
        Xs[c4 + 2][r] = vx.z;
        Xs[c4 + 3][r] = vx.w;
        *(float4*)&Ws[r][c8]     = vw0;
        *(float4*)&Ws[r][c8 + 4] = vw1;
        __syncthreads();
        if (k0 + 32 < K) {   // prefetch next K-tile while FMAs run
            const int xb = r * K + k0 + 32 + c4;
            if (XC) {
                vx.x = ldc(&Xrow[xb + 0]);
                vx.y = ldc(&Xrow[xb + 1]);
                vx.z = ldc(&Xrow[xb + 2]);
                vx.w = ldc(&Xrow[xb + 3]);
            } else {
                vx = *(const float4*)&Xrow[xb];
            }
            vw0 = *(const float4*)&Wcol[(k0 + 32 + r) * N + c8];
            vw1 = *(const float4*)&Wcol[(k0 + 32 + r) * N + c8 + 4];
        }
        #pragma unroll
        for (int kk = 0; kk < 32; kk++) {
            float4 b = *(const float4*)&Ws[kk][tx << 2];
            float2 a = *(const float2*)&Xs[kk][ty2];
            acc[0][0] += a.x * b.x; acc[0][1] += a.x * b.y;
            acc[0][2] += a.x * b.z; acc[0][3] += a.x * b.w;
            acc[1][0] += a.y * b.x; acc[1][1] += a.y * b.y;
            acc[1][2] += a.y * b.z; acc[1][3] += a.y * b.w;
        }
        __syncthreads();
    }
}

struct KArgs {
    const float* qf;  const float* sf;  const int* y;
    const float* Wn1; const float* bn1; const float* Wn2; const float* bn2;
    const float* Wm1; const float* bm1; const float* Wm2; const float* bm2;
    const float* Wr1; const float* br1; const float* wr2; const float* br2;
    float* out; float* ws;
};

// ---------------------------------------------------------------------------
// Single persistent kernel, plain launch, 256 blocks x 256 threads (R4's
// faster mapping). Phases separated by the fence-free grid barrier:
//  P0 enc1(192 tiles)+stats | P1 enc2(192) |
//  [ab(128)+hq(128,t==0) | hsum(256x2) | gagg(64)] x3 | hsT(64) | scores(256x2)
// All intermediates go through sc1 (LLC); weights stay L2-cached throughout.
// ---------------------------------------------------------------------------
__global__ __launch_bounds__(256) void fused_k(KArgs a) {
    __shared__ float Xs[32][66];
    __shared__ float Ws[32][68];
    __shared__ int   lst[SS];
    __shared__ int   info[2];
    __shared__ int   lc[16];
    __shared__ float hqs[4][HH];
    __shared__ float w2s[HH];

    float* F    = a.ws;
    float* X1   = F + 0;             // 1536*256 (dead after enc2)
    float* QS   = F + 393216;        // 1536*256
    float* q    = QS;                // 1024*256
    float* s    = QS + QQ * HH;      // 512*256
    float* A    = F + 786432;        // 512*256
    float* Bm   = F + 917504;        // 512*256
    float* hsum = F + 1048576;       // 512*256
    float* hq   = F + 0;             // 1024*256 (reuses dead X1)
    float* hsT  = F + 262144;        // 256*512  (inside dead X1)
    float* cntf = F + 1179648;       // 512
    float* invd = F + 1180160;       // 512
    int*  icls  = (int*)(F + 1180672);
    int*  cls_cnt  = icls;           // 16
    int*  cls_list = icls + 16;      // 16*512
    unsigned int* bar = (unsigned int*)(F + 1200128);  // zeroed by host memset

    const int tid = threadIdx.x;
    const int bid = blockIdx.x;
    const int tx  = tid & 15, ty2 = (tid >> 4) << 1;
    unsigned int gen = 0;            // barrier generation (thread 0's copy used)

    // ---------------- P0: enc1 (relu(x@Wn1+bn1)) + mask statistics ---------
    if (bid < 192) {
        const int m0 = (bid >> 2) << 5;
        const int n0 = (bid & 3) << 6;
        const float* Xrow = (m0 < QQ) ? (a.qf + m0 * EE) : (a.sf + (m0 - QQ) * EE);
        float acc[2][4] = {{0,0,0,0},{0,0,0,0}};
        mm_tile<false>(Xrow, EE, a.Wn1 + n0, HH, Xs, Ws, acc);
        #pragma unroll
        for (int rr = 0; rr < 2; rr++) {
            int m = m0 + ty2 + rr;
            int n = n0 + (tx << 2);
            float* xp = &X1[m * HH + n];
            stc(xp + 0, fmaxf(acc[rr][0] + a.bn1[n + 0], 0.f));
            stc(xp + 1, fmaxf(acc[rr][1] + a.bn1[n + 1], 0.f));
            stc(xp + 2, fmaxf(acc[rr][2] + a.bn1[n + 2], 0.f));
            stc(xp + 3, fmaxf(acc[rr][3] + a.bn1[n + 3], 0.f));
        }
    } else if (bid == 192) {
        if (tid < 16) lc[tid] = 0;
        __syncthreads();
        for (int i = tid; i < SS; i += 256) {
            int c = a.y[i];
            int slot = atomicAdd(&lc[c], 1);
            stci(&cls_list[c * SS + slot], i);
        }
        __syncthreads();
        if (tid < 16) stci(&cls_cnt[tid], lc[tid]);
        for (int i = tid; i < SS; i += 256) {
            float n = (float)(lc[a.y[i]] - 1);
            stc(&cntf[i], n);
            stc(&invd[i], 1.f / fmaxf(n, 1.f));
        }
    }
    gbar(bar, &gen);

    // ---------------- P1: enc2 (X1@Wn2+bn2) -> QS --------------------------
    if (bid < 192) {
        const int m0 = (bid >> 2) << 5;
        const int n0 = (bid & 3) << 6;
        float acc[2][4] = {{0,0,0,0},{0,0,0,0}};
        mm_tile<true>(X1 + m0 * HH, HH, a.Wn2 + n0, HH, Xs, Ws, acc);
        #pragma unroll
        for (int rr = 0; rr < 2; rr++) {
            int m = m0 + ty2 + rr;
            int n = n0 + (tx << 2);
            float* qp = &QS[m * HH + n];
            stc(qp + 0, acc[rr][0] + a.bn2[n + 0]);
            stc(qp + 1, acc[rr][1] + a.bn2[n + 1]);
            stc(qp + 2, acc[rr][2] + a.bn2[n + 2]);
            stc(qp + 3, acc[rr][3] + a.bn2[n + 3]);
        }
    }
    gbar(bar, &gen);

    // ---------------- message passing --------------------------------------
    for (int t = 0; t < NSTEPS; t++) {
        const float* W1t = a.Wm1 + t * 2 * HH * HH;
        const float* b1t = a.bm1 + t * HH;
        const float* W2t = a.Wm2 + t * HH * HH;
        const float* b2t = a.bm2 + t * HH;

        // ab: A = s@W1a, B = s@W1b  (+ hq = q@Wr1a co-scheduled at t==0)
        if (bid < 128) {
            int nt = bid & 7;
            const int m0 = (bid >> 3) << 5;
            const float* W = W1t;
            float* C = A;
            if (nt >= 4) { nt -= 4; W = W1t + HH * HH; C = Bm; }
            const int n0 = nt << 6;
            float acc[2][4] = {{0,0,0,0},{0,0,0,0}};
            mm_tile<true>(s + m0 * HH, HH, W + n0, HH, Xs, Ws, acc);
            #pragma unroll
            for (int rr = 0; rr < 2; rr++) {
                int m = m0 + ty2 + rr;
                int n = n0 + (tx << 2);
                float* cp = &C[m * HH + n];
                stc(cp + 0, acc[rr][0]);
                stc(cp + 1, acc[rr][1]);
                stc(cp + 2, acc[rr][2]);
                stc(cp + 3, acc[rr][3]);
            }
        } else if (t == 0) {
            const int idx = bid - 128;        // 0..127
            const int m0 = (idx >> 2) << 5;   // 32 row tiles over Q=1024
            const int n0 = (idx & 3) << 6;
            float acc[2][4] = {{0,0,0,0},{0,0,0,0}};
            mm_tile<true>(q + m0 * HH, HH, a.Wr1 + n0, HH, Xs, Ws, acc);
            #pragma unroll
            for (int rr = 0; rr < 2; rr++) {
                int m = m0 + ty2 + rr;
                int n = n0 + (tx << 2);
                float* hp = &hq[m * HH + n];
                stc(hp + 0, acc[rr][0]);
                stc(hp + 1, acc[rr][1]);
                stc(hp + 2, acc[rr][2]);
                stc(hp + 3, acc[rr][3]);
            }
        }
        gbar(bar, &gen);

        // hsum: 2 support rows per block (bid, bid+256)
        #pragma unroll
        for (int rep = 0; rep < 2; rep++) {
            const int i = bid + (rep << 8);
            const int h = tid;
            __syncthreads();                 // protect info/lst rewrite
            if (h == 0) { int yi = a.y[i]; info[0] = yi; info[1] = ldci(&cls_cnt[yi]); }
            __syncthreads();
            const int cnt = info[1];
            const int* Lp = cls_list + info[0] * SS;
            for (int m = h; m < cnt; m += 256) lst[m] = ldci(&Lp[m]);
            __syncthreads();
            const float av = ldc(&A[i * HH + h]) + b1t[h];
            float acc = 0.f;
            int m = 0;
            for (; m + 4 <= cnt; m += 4) {          // 4 loads in flight
                float v0 = ldc(&Bm[lst[m + 0] * HH + h]);
                float v1 = ldc(&Bm[lst[m + 1] * HH + h]);
                float v2 = ldc(&Bm[lst[m + 2] * HH + h]);
                float v3 = ldc(&Bm[lst[m + 3] * HH + h]);
                acc += fmaxf(av + v0, 0.f) + fmaxf(av + v1, 0.f)
                     + fmaxf(av + v2, 0.f) + fmaxf(av + v3, 0.f);
            }
            for (; m < cnt; m++) acc += fmaxf(av + ldc(&Bm[lst[m] * HH + h]), 0.f);
            acc -= fmaxf(av + ldc(&Bm[i * HH + h]), 0.f);  // remove self term
            stc(&hsum[i * HH + h], acc);
        }
        gbar(bar, &gen);

        // gagg: s += (hsum@W2 + cnt*bm2) * invd
        if (bid < 64) {
            const int m0 = (bid >> 2) << 5;
            const int n0 = (bid & 3) << 6;
            float acc[2][4] = {{0,0,0,0},{0,0,0,0}};
            mm_tile<true>(hsum + m0 * HH, HH, W2t + n0, HH, Xs, Ws, acc);
            #pragma unroll
            for (int rr = 0; rr < 2; rr++) {
                int m = m0 + ty2 + rr;
                int n = n0 + (tx << 2);
                float ci = ldc(&cntf[m]), di = ldc(&invd[m]);
                float* sp = &s[m * HH + n];
                stc(sp + 0, ldc(sp + 0) + (acc[rr][0] + ci * b2t[n + 0]) * di);
                stc(sp + 1, ldc(sp + 1) + (acc[rr][1] + ci * b2t[n + 1]) * di);
                stc(sp + 2, ldc(sp + 2) + (acc[rr][2] + ci * b2t[n + 2]) * di);
                stc(sp + 3, ldc(sp + 3) + (acc[rr][3] + ci * b2t[n + 3]) * di);
            }
        }
        gbar(bar, &gen);
    }

    // ---------------- hsT[h][j] = (s@Wr1b)[j][h] + br1[h] -------------------
    if (bid < 64) {
        const int m0 = (bid >> 2) << 5;
        const int n0 = (bid & 3) << 6;
        float acc[2][4] = {{0,0,0,0},{0,0,0,0}};
        mm_tile<true>(s + m0 * HH, HH, a.Wr1 + HH * HH + n0, HH, Xs, Ws, acc);
        #pragma unroll
        for (int rr = 0; rr < 2; rr++) {
            int m = m0 + ty2 + rr;
            #pragma unroll
            for (int c = 0; c < 4; c++) {
                int n = n0 + (tx << 2) + c;
                stc(&hsT[n * SS + m], acc[rr][c] + a.br1[n]);
            }
        }
    }
    gbar(bar, &gen);

    // ---------------- scores: 4 hq rows per block, both j-halves -----------
    {
        const int i0 = bid << 2;
        w2s[tid] = a.wr2[tid];
        #pragma unroll
        for (int ii = 0; ii < 4; ii++) hqs[ii][tid] = ldc(&hq[(i0 + ii) * HH + tid]);
        __syncthreads();
        const float b2 = a.br2[0];
        #pragma unroll
        for (int jh = 0; jh < 2; jh++) {
            const int j = (jh << 8) + tid;
            float acc[4] = {0, 0, 0, 0};
            for (int h0 = 0; h0 < HH; h0 += 8) {
                float v[8];
                #pragma unroll
                for (int u = 0; u < 8; u++) v[u] = ldc(&hsT[(h0 + u) * SS + j]);
                float4 w0 = *(const float4*)&w2s[h0];
                float4 w1 = *(const float4*)&w2s[h0 + 4];
                #pragma unroll
                for (int ii = 0; ii < 4; ii++) {
                    float4 a0 = *(const float4*)&hqs[ii][h0];
                    float4 a1 = *(const float4*)&hqs[ii][h0 + 4];
                    acc[ii] += fmaxf(v[0] + a0.x, 0.f) * w0.x
                             + fmaxf(v[1] + a0.y, 0.f) * w0.y
                             + fmaxf(v[2] + a0.z, 0.f) * w0.z
                             + fmaxf(v[3] + a0.w, 0.f) * w0.w
                             + fmaxf(v[4] + a1.x, 0.f) * w1.x
                             + fmaxf(v[5] + a1.y, 0.f) * w1.y
                             + fmaxf(v[6] + a1.z, 0.f) * w1.z
                             + fmaxf(v[7] + a1.w, 0.f) * w1.w;
                }
            }
            #pragma unroll
            for (int ii = 0; ii < 4; ii++)
                a.out[(i0 + ii) * SS + j] = acc[ii] + b2;
        }
    }
}

extern "C" void kernel_launch(void* const* d_in, const int* in_sizes, int n_in,
                              void* d_out, int out_size, void* d_ws, size_t ws_size,
                              hipStream_t stream) {
    KArgs ka;
    ka.qf  = (const float*)d_in[0];
    ka.sf  = (const float*)d_in[1];
    ka.y   = (const int*)d_in[2];
    ka.Wn1 = (const float*)d_in[3];
    ka.bn1 = (const float*)d_in[4];
    ka.Wn2 = (const float*)d_in[5];
    ka.bn2 = (const float*)d_in[6];
    ka.Wm1 = (const float*)d_in[7];
    ka.bm1 = (const float*)d_in[8];
    ka.Wm2 = (const float*)d_in[9];
    ka.bm2 = (const float*)d_in[10];
    ka.Wr1 = (const float*)d_in[11];
    ka.br1 = (const float*)d_in[12];
    ka.wr2 = (const float*)d_in[13];
    ka.br2 = (const float*)d_in[14];
    ka.out = (float*)d_out;
    ka.ws  = (float*)d_ws;

    // zero the grid-barrier state (gen + ping-pong counters, 3 cache lines)
    hipMemsetAsync((char*)d_ws + 1200128u * sizeof(float), 0, 384, stream);

    fused_k<<<dim3(NBLK), dim3(256), 0, stream>>>(ka);
}

// Round 7
// 274.267 us; speedup vs baseline: 1.3075x; 1.0202x over previous
//
#include <hip/hip_runtime.h>

#define EE 512
#define HH 256
#define QQ 1024
#define SS 512
#define NSTEPS 3
#define NBLK 256

// ---------------------------------------------------------------------------
// Coherence protocol (R6 post-mortem): PRODUCERS write intermediates with
// sc1 write-through stores (data lands at the LLC coherence point, no
// release wbl2 walk needed). CONSUMERS use PLAIN CACHED loads -- re-reads
// hit L2/L1 -- made safe by ONE acquire fence (buffer_inv sc0 sc1: L1+L2
// invalidate) per grid barrier. R6's sc1 LOADS bypassed L2 every access and
// cost ~500cy x every reuse (hsum's Bm ~32x reuse alone ~40us).
// ---------------------------------------------------------------------------
__device__ __forceinline__ void stc(float* p, float v) {
    __hip_atomic_store(p, v, __ATOMIC_RELAXED, __HIP_MEMORY_SCOPE_AGENT);
}
__device__ __forceinline__ void stci(int* p, int v) {
    __hip_atomic_store(p, v, __ATOMIC_RELAXED, __HIP_MEMORY_SCOPE_AGENT);
}
__device__ __forceinline__ void stc2(float* p, float x, float y) {
    unsigned long long v = ((unsigned long long)__float_as_uint(y) << 32)
                         | (unsigned long long)__float_as_uint(x);
    __hip_atomic_store((unsigned long long*)p, v, __ATOMIC_RELAXED,
                       __HIP_MEMORY_SCOPE_AGENT);
}
__device__ __forceinline__ void stc4(float* p, float4 o) {
    stc2(p + 0, o.x, o.y);
    stc2(p + 2, o.z, o.w);
}

// ---------------------------------------------------------------------------
// Grid barrier: arrival fetch_add + relaxed poll (no release fence -- sc1
// stores are already at the coherence point once vmcnt drains at the entry
// __syncthreads) + ONE acquire fence after the flip is observed so the next
// phase's plain loads refetch fresh data into L2/L1. Ping-pong counters.
// 256 blocks = 1/CU guaranteed resident (24.4KB LDS -> 6 blocks/CU capacity).
// ---------------------------------------------------------------------------
__device__ __forceinline__ void gbar(unsigned int* bar, unsigned int* gen) {
    __syncthreads();                       // drains vmcnt: sc1 stores at LLC
    if (threadIdx.x == 0) {
        const unsigned int g = *gen;
        unsigned int* cnt = &bar[32 + ((g & 1u) << 5)];
        unsigned int arrived = __hip_atomic_fetch_add(
            cnt, 1u, __ATOMIC_RELAXED, __HIP_MEMORY_SCOPE_AGENT);
        if (arrived == NBLK - 1u) {
            __hip_atomic_store(cnt, 0u, __ATOMIC_RELAXED,
                               __HIP_MEMORY_SCOPE_AGENT);
            asm volatile("s_waitcnt vmcnt(0)" ::: "memory"); // reset lands 1st
            __hip_atomic_store(&bar[0], g + 1u, __ATOMIC_RELAXED,
                               __HIP_MEMORY_SCOPE_AGENT);
        } else {
            while (__hip_atomic_load(&bar[0], __ATOMIC_RELAXED,
                                     __HIP_MEMORY_SCOPE_AGENT) < g + 1u) {
                __builtin_amdgcn_s_sleep(2);
            }
        }
        __builtin_amdgcn_fence(__ATOMIC_ACQUIRE, "agent");  // L1+L2 inv (once)
        *gen = g + 1u;
    }
    __syncthreads();
}

// ---------------------------------------------------------------------------
// 32x64 GEMM tile engine: 256 threads, BK=32, register-prefetch double
// buffering, plain cached float4 loads for both operands (intermediate X is
// valid to read cached thanks to the barrier acquire-inv).
// X-tile stored K-MAJOR (Xs[k][m], stride 66); acc[2][4].
// ---------------------------------------------------------------------------
__device__ __forceinline__ void mm_tile(const float* __restrict__ Xrow, int K,
                                        const float* __restrict__ Wcol, int N,
                                        float (*Xs)[66], float (*Ws)[68],
                                        float acc[2][4]) {
    const int tid = threadIdx.x;
    const int r   = tid >> 3;          // 0..31
    const int c4  = (tid & 7) << 2;    // X k-chunk
    const int c8  = (tid & 7) << 3;    // W n-chunk
    const int tx  = tid & 15;
    const int ty2 = (tid >> 4) << 1;   // row pair base

    float4 vx  = *(const float4*)&Xrow[r * K + c4];
    float4 vw0 = *(const float4*)&Wcol[r * N + c8];
    float4 vw1 = *(const float4*)&Wcol[r * N + c8 + 4];

    for (int k0 = 0; k0 < K; k0 += 32) {
        Xs[c4 + 0][r] = vx.x;          // k-major scatter (2-way conflicts max)
        Xs[c4 + 1][r] = vx.y;
        Xs[c4 + 2][r] = vx.z;
        Xs[c4 + 3][r] = vx.w;
        *(float4*)&Ws[r][c8]     = vw0;
        *(float4*)&Ws[r][c8 + 4] = vw1;
        __syncthreads();
        if (k0 + 32 < K) {   // prefetch next K-tile while FMAs run
            vx  = *(const float4*)&Xrow[r * K + k0 + 32 + c4];
            vw0 = *(const float4*)&Wcol[(k0 + 32 + r) * N + c8];
            vw1 = *(const float4*)&Wcol[(k0 + 32 + r) * N + c8 + 4];
        }
        #pragma unroll
        for (int kk = 0; kk < 32; kk++) {
            float4 b = *(const float4*)&Ws[kk][tx << 2];
            float2 a = *(const float2*)&Xs[kk][ty2];
            acc[0][0] += a.x * b.x; acc[0][1] += a.x * b.y;
            acc[0][2] += a.x * b.z; acc[0][3] += a.x * b.w;
            acc[1][0] += a.y * b.x; acc[1][1] += a.y * b.y;
            acc[1][2] += a.y * b.z; acc[1][3] += a.y * b.w;
        }
        __syncthreads();
    }
}

struct KArgs {
    const float* qf;  const float* sf;  const int* y;
    const float* Wn1; const float* bn1; const float* Wn2; const float* bn2;
    const float* Wm1; const float* bm1; const float* Wm2; const float* bm2;
    const float* Wr1; const float* br1; const float* wr2; const float* br2;
    float* out; float* ws;
};

// ---------------------------------------------------------------------------
// Single persistent kernel, 256 blocks x 256 threads. Phases:
//  P0 enc1(192 tiles)+stats | P1 enc2(192) |
//  [ab(128)+hq(128,t==0) | hsum(256x2) | gagg(64)] x3 | hsT(64) | scores(256x2)
// sc1 stores for intermediates; plain cached loads + per-barrier acquire-inv.
// ---------------------------------------------------------------------------
__global__ __launch_bounds__(256) void fused_k(KArgs a) {
    __shared__ float Xs[32][66];
    __shared__ float Ws[32][68];
    __shared__ int   lst[SS];
    __shared__ int   info[2];
    __shared__ int   lc[16];
    __shared__ float hqs[4][HH];
    __shared__ float w2s[HH];

    float* F    = a.ws;
    float* X1   = F + 0;             // 1536*256 (dead after enc2)
    float* QS   = F + 393216;        // 1536*256
    float* q    = QS;                // 1024*256
    float* s    = QS + QQ * HH;      // 512*256
    float* A    = F + 786432;        // 512*256
    float* Bm   = F + 917504;        // 512*256
    float* hsum = F + 1048576;       // 512*256
    float* hq   = F + 0;             // 1024*256 (reuses dead X1)
    float* hsT  = F + 262144;        // 256*512  (inside dead X1)
    float* cntf = F + 1179648;       // 512
    float* invd = F + 1180160;       // 512
    int*  icls  = (int*)(F + 1180672);
    int*  cls_cnt  = icls;           // 16
    int*  cls_list = icls + 16;      // 16*512
    unsigned int* bar = (unsigned int*)(F + 1200128);  // zeroed by host memset

    const int tid = threadIdx.x;
    const int bid = blockIdx.x;
    const int tx  = tid & 15, ty2 = (tid >> 4) << 1;
    unsigned int gen = 0;            // barrier generation (thread 0's copy used)

    // ---------------- P0: enc1 (relu(x@Wn1+bn1)) + mask statistics ---------
    if (bid < 192) {
        const int m0 = (bid >> 2) << 5;
        const int n0 = (bid & 3) << 6;
        const float* Xrow = (m0 < QQ) ? (a.qf + m0 * EE) : (a.sf + (m0 - QQ) * EE);
        float acc[2][4] = {{0,0,0,0},{0,0,0,0}};
        mm_tile(Xrow, EE, a.Wn1 + n0, HH, Xs, Ws, acc);
        #pragma unroll
        for (int rr = 0; rr < 2; rr++) {
            int m = m0 + ty2 + rr;
            int n = n0 + (tx << 2);
            float4 o;
            o.x = fmaxf(acc[rr][0] + a.bn1[n + 0], 0.f);
            o.y = fmaxf(acc[rr][1] + a.bn1[n + 1], 0.f);
            o.z = fmaxf(acc[rr][2] + a.bn1[n + 2], 0.f);
            o.w = fmaxf(acc[rr][3] + a.bn1[n + 3], 0.f);
            stc4(&X1[m * HH + n], o);
        }
    } else if (bid == 192) {
        if (tid < 16) lc[tid] = 0;
        __syncthreads();
        for (int i = tid; i < SS; i += 256) {
            int c = a.y[i];
            int slot = atomicAdd(&lc[c], 1);
            stci(&cls_list[c * SS + slot], i);
        }
        __syncthreads();
        if (tid < 16) stci(&cls_cnt[tid], lc[tid]);
        for (int i = tid; i < SS; i += 256) {
            float n = (float)(lc[a.y[i]] - 1);
            stc(&cntf[i], n);
            stc(&invd[i], 1.f / fmaxf(n, 1.f));
        }
    }
    gbar(bar, &gen);

    // ---------------- P1: enc2 (X1@Wn2+bn2) -> QS --------------------------
    if (bid < 192) {
        const int m0 = (bid >> 2) << 5;
        const int n0 = (bid & 3) << 6;
        float acc[2][4] = {{0,0,0,0},{0,0,0,0}};
        mm_tile(X1 + m0 * HH, HH, a.Wn2 + n0, HH, Xs, Ws, acc);
        #pragma unroll
        for (int rr = 0; rr < 2; rr++) {
            int m = m0 + ty2 + rr;
            int n = n0 + (tx << 2);
            float4 o;
            o.x = acc[rr][0] + a.bn2[n + 0];
            o.y = acc[rr][1] + a.bn2[n + 1];
            o.z = acc[rr][2] + a.bn2[n + 2];
            o.w = acc[rr][3] + a.bn2[n + 3];
            stc4(&QS[m * HH + n], o);
        }
    }
    gbar(bar, &gen);

    // ---------------- message passing --------------------------------------
    for (int t = 0; t < NSTEPS; t++) {
        const float* W1t = a.Wm1 + t * 2 * HH * HH;
        const float* b1t = a.bm1 + t * HH;
        const float* W2t = a.Wm2 + t * HH * HH;
        const float* b2t = a.bm2 + t * HH;

        // ab: A = s@W1a, B = s@W1b  (+ hq = q@Wr1a co-scheduled at t==0)
        if (bid < 128) {
            int nt = bid & 7;
            const int m0 = (bid >> 3) << 5;
            const float* W = W1t;
            float* C = A;
            if (nt >= 4) { nt -= 4; W = W1t + HH * HH; C = Bm; }
            const int n0 = nt << 6;
            float acc[2][4] = {{0,0,0,0},{0,0,0,0}};
            mm_tile(s + m0 * HH, HH, W + n0, HH, Xs, Ws, acc);
            #pragma unroll
            for (int rr = 0; rr < 2; rr++) {
                int m = m0 + ty2 + rr;
                int n = n0 + (tx << 2);
                float4 o = { acc[rr][0], acc[rr][1], acc[rr][2], acc[rr][3] };
                stc4(&C[m * HH + n], o);
            }
        } else if (t == 0) {
            const int idx = bid - 128;        // 0..127
            const int m0 = (idx >> 2) << 5;   // 32 row tiles over Q=1024
            const int n0 = (idx & 3) << 6;
            float acc[2][4] = {{0,0,0,0},{0,0,0,0}};
            mm_tile(q + m0 * HH, HH, a.Wr1 + n0, HH, Xs, Ws, acc);
            #pragma unroll
            for (int rr = 0; rr < 2; rr++) {
                int m = m0 + ty2 + rr;
                int n = n0 + (tx << 2);
                float4 o = { acc[rr][0], acc[rr][1], acc[rr][2], acc[rr][3] };
                stc4(&hq[m * HH + n], o);
            }
        }
        gbar(bar, &gen);

        // hsum: 2 support rows per block (bid, bid+256)
        #pragma unroll
        for (int rep = 0; rep < 2; rep++) {
            const int i = bid + (rep << 8);
            const int h = tid;
            __syncthreads();                 // protect info/lst rewrite
            if (h == 0) { int yi = a.y[i]; info[0] = yi; info[1] = cls_cnt[yi]; }
            __syncthreads();
            const int cnt = info[1];
            const int* Lp = cls_list + info[0] * SS;
            for (int m = h; m < cnt; m += 256) lst[m] = Lp[m];
            __syncthreads();
            const float av = A[i * HH + h] + b1t[h];
            float acc = 0.f;
            int m = 0;
            for (; m + 4 <= cnt; m += 4) {          // 4 loads in flight
                float v0 = Bm[lst[m + 0] * HH + h];
                float v1 = Bm[lst[m + 1] * HH + h];
                float v2 = Bm[lst[m + 2] * HH + h];
                float v3 = Bm[lst[m + 3] * HH + h];
                acc += fmaxf(av + v0, 0.f) + fmaxf(av + v1, 0.f)
                     + fmaxf(av + v2, 0.f) + fmaxf(av + v3, 0.f);
            }
            for (; m < cnt; m++) acc += fmaxf(av + Bm[lst[m] * HH + h], 0.f);
            acc -= fmaxf(av + Bm[i * HH + h], 0.f);  // remove self term
            stc(&hsum[i * HH + h], acc);
        }
        gbar(bar, &gen);

        // gagg: s += (hsum@W2 + cnt*bm2) * invd
        if (bid < 64) {
            const int m0 = (bid >> 2) << 5;
            const int n0 = (bid & 3) << 6;
            float acc[2][4] = {{0,0,0,0},{0,0,0,0}};
            mm_tile(hsum + m0 * HH, HH, W2t + n0, HH, Xs, Ws, acc);
            #pragma unroll
            for (int rr = 0; rr < 2; rr++) {
                int m = m0 + ty2 + rr;
                int n = n0 + (tx << 2);
                float ci = cntf[m], di = invd[m];
                float* sp = &s[m * HH + n];
                float4 sv = *(const float4*)sp;
                float4 o;
                o.x = sv.x + (acc[rr][0] + ci * b2t[n + 0]) * di;
                o.y = sv.y + (acc[rr][1] + ci * b2t[n + 1]) * di;
                o.z = sv.z + (acc[rr][2] + ci * b2t[n + 2]) * di;
                o.w = sv.w + (acc[rr][3] + ci * b2t[n + 3]) * di;
                stc4(sp, o);
            }
        }
        gbar(bar, &gen);
    }

    // ---------------- hsT[h][j] = (s@Wr1b)[j][h] + br1[h] -------------------
    if (bid < 64) {
        const int m0 = (bid >> 2) << 5;
        const int n0 = (bid & 3) << 6;
        float acc[2][4] = {{0,0,0,0},{0,0,0,0}};
        mm_tile(s + m0 * HH, HH, a.Wr1 + HH * HH + n0, HH, Xs, Ws, acc);
        #pragma unroll
        for (int rr = 0; rr < 2; rr++) {
            int m = m0 + ty2 + rr;
            #pragma unroll
            for (int c = 0; c < 4; c++) {
                int n = n0 + (tx << 2) + c;
                stc(&hsT[n * SS + m], acc[rr][c] + a.br1[n]);
            }
        }
    }
    gbar(bar, &gen);

    // ---------------- scores: 4 hq rows per block, both j-halves -----------
    {
        const int i0 = bid << 2;
        w2s[tid] = a.wr2[tid];
        #pragma unroll
        for (int ii = 0; ii < 4; ii++) hqs[ii][tid] = hq[(i0 + ii) * HH + tid];
        __syncthreads();
        const float b2 = a.br2[0];
        #pragma unroll
        for (int jh = 0; jh < 2; jh++) {
            const int j = (jh << 8) + tid;
            float acc[4] = {0, 0, 0, 0};
            for (int h0 = 0; h0 < HH; h0 += 8) {
                float v[8];
                #pragma unroll
                for (int u = 0; u < 8; u++) v[u] = hsT[(h0 + u) * SS + j];
                float4 w0 = *(const float4*)&w2s[h0];
                float4 w1 = *(const float4*)&w2s[h0 + 4];
                #pragma unroll
                for (int ii = 0; ii < 4; ii++) {
                    float4 a0 = *(const float4*)&hqs[ii][h0];
                    float4 a1 = *(const float4*)&hqs[ii][h0 + 4];
                    acc[ii] += fmaxf(v[0] + a0.x, 0.f) * w0.x
                             + fmaxf(v[1] + a0.y, 0.f) * w0.y
                             + fmaxf(v[2] + a0.z, 0.f) * w0.z
                             + fmaxf(v[3] + a0.w, 0.f) * w0.w
                             + fmaxf(v[4] + a1.x, 0.f) * w1.x
                             + fmaxf(v[5] + a1.y, 0.f) * w1.y
                             + fmaxf(v[6] + a1.z, 0.f) * w1.z
                             + fmaxf(v[7] + a1.w, 0.f) * w1.w;
                }
            }
            #pragma unroll
            for (int ii = 0; ii < 4; ii++)
                a.out[(i0 + ii) * SS + j] = acc[ii] + b2;
        }
    }
}

extern "C" void kernel_launch(void* const* d_in, const int* in_sizes, int n_in,
                              void* d_out, int out_size, void* d_ws, size_t ws_size,
                              hipStream_t stream) {
    KArgs ka;
    ka.qf  = (const float*)d_in[0];
    ka.sf  = (const float*)d_in[1];
    ka.y   = (const int*)d_in[2];
    ka.Wn1 = (const float*)d_in[3];
    ka.bn1 = (const float*)d_in[4];
    ka.Wn2 = (const float*)d_in[5];
    ka.bn2 = (const float*)d_in[6];
    ka.Wm1 = (const float*)d_in[7];
    ka.bm1 = (const float*)d_in[8];
    ka.Wm2 = (const float*)d_in[9];
    ka.bm2 = (const float*)d_in[10];
    ka.Wr1 = (const float*)d_in[11];
    ka.br1 = (const float*)d_in[12];
    ka.wr2 = (const float*)d_in[13];
    ka.br2 = (const float*)d_in[14];
    ka.out = (float*)d_out;
    ka.ws  = (float*)d_ws;

    // zero the grid-barrier state (gen + ping-pong counters, 3 cache lines)
    hipMemsetAsync((char*)d_ws + 1200128u * sizeof(float), 0, 384, stream);

    fused_k<<<dim3(NBLK), dim3(256), 0, stream>>>(ka);
}